// Round 1
// baseline (511.589 us; speedup 1.0000x reference)
//
#include <hip/hip_runtime.h>
#include <climits>

#define HW 262144          // 512*512
#define IW 512
#define RN 725             // rotated canvas side
#define RHW 525625         // 725*725
#define NSEG 256
#define CH_OFF 1536
#define TH_OFF 116736
#define XY_OFF 485376

static __device__ __forceinline__ float loadpix(const float* p, int y, int x, int n) {
    return (y >= 0 && y < n && x >= 0 && x < n) ? p[y * n + x] : 0.0f;
}

// ---- rotate img by +45 into 725x725 canvas (nearest) ----
__global__ void k_rot(const float* __restrict__ img, float* __restrict__ rot) {
    int p = blockIdx.x * blockDim.x + threadIdx.x;
    if (p >= RHW) return;
    int bc = blockIdx.y;                 // b*3+c, 6 images
    int y = p / RN;
    int x = p - y * RN;
    const float cs = 0.7071067811865476f;   // cos45 == sin45 in f32
    float xg = (float)x - 362.0f;           // (725-1)/2
    float yg = (float)y - 362.0f;
    float xi = cs * xg - cs * yg + 255.5f;  // c*xg - s*yg + (W-1)/2
    float yi = cs * xg + cs * yg + 255.5f;  // s*xg + c*yg + (H-1)/2
    int xn = (int)rintf(xi);
    int yn = (int)rintf(yi);
    float v = 0.0f;
    if (xn >= 0 && xn < IW && yn >= 0 && yn < IW)
        v = img[(size_t)bc * HW + yn * IW + xn];
    rot[(size_t)bc * RHW + p] = v;
}

// ---- Scharr (cross-correlation, SAME zero pad) on the 512x512 image ----
__global__ void k_scharr_img(const float* __restrict__ img, float* __restrict__ g) {
    int p = blockIdx.x * blockDim.x + threadIdx.x;
    if (p >= HW) return;
    int bc = blockIdx.y;
    int y = p >> 9, x = p & 511;
    const float* im = img + (size_t)bc * HW;
    float a = loadpix(im, y - 1, x - 1, IW), b = loadpix(im, y - 1, x, IW), c = loadpix(im, y - 1, x + 1, IW);
    float d = loadpix(im, y, x - 1, IW), e = loadpix(im, y, x + 1, IW);
    float f = loadpix(im, y + 1, x - 1, IW), h = loadpix(im, y + 1, x, IW), i = loadpix(im, y + 1, x + 1, IW);
    // kx = [[-3,0,3],[10,0,10],[-3,0,3]] (as given), ky = kx.T
    float g0 = -3.f * a + 3.f * c + 10.f * d + 10.f * e - 3.f * f + 3.f * i;
    float g1 = -3.f * a + 10.f * b - 3.f * c + 3.f * f + 10.f * h + 3.f * i;
    g[((size_t)bc * 2 + 0) * HW + p] = g0;
    g[((size_t)bc * 2 + 1) * HW + p] = g1;
}

// ---- fused: rotate-back(-45) sample position + Scharr of rot at source, cropped [105:617] ----
__global__ void k_grc(const float* __restrict__ rot, float* __restrict__ grc) {
    int p = blockIdx.x * blockDim.x + threadIdx.x;
    if (p >= HW) return;
    int bc = blockIdx.y;
    int y = p >> 9, x = p & 511;
    const float cs = 0.7071067811865476f;  // cos(-45); sin(-45) = -cs
    float xg = (float)(x + 105) - 512.5f;  // (1026-1)/2
    float yg = (float)(y + 105) - 512.5f;
    float t1 = cs * xg, t2 = cs * yg;
    float xi = (t1 + t2) + 362.0f;   // c*xg - s*yg + (725-1)/2
    float yi = (-t1 + t2) + 362.0f;  // s*xg + c*yg + ...
    int xn = (int)rintf(xi);
    int yn = (int)rintf(yi);
    float g0 = 0.f, g1 = 0.f;
    if (xn >= 0 && xn < RN && yn >= 0 && yn < RN) {
        const float* im = rot + (size_t)bc * RHW;
        float a = loadpix(im, yn - 1, xn - 1, RN), b = loadpix(im, yn - 1, xn, RN), c = loadpix(im, yn - 1, xn + 1, RN);
        float d = loadpix(im, yn, xn - 1, RN), e = loadpix(im, yn, xn + 1, RN);
        float f = loadpix(im, yn + 1, xn - 1, RN), h = loadpix(im, yn + 1, xn, RN), i = loadpix(im, yn + 1, xn + 1, RN);
        g0 = -3.f * a + 3.f * c + 10.f * d + 10.f * e - 3.f * f + 3.f * i;
        g1 = -3.f * a + 10.f * b - 3.f * c + 3.f * f + 10.f * h + 3.f * i;
    }
    grc[((size_t)bc * 2 + 0) * HW + p] = g0;
    grc[((size_t)bc * 2 + 1) * HW + p] = g1;
}

// ---- per-map min/max over 512^2 (24 maps: 12 g then 12 grc, contiguous) ----
__global__ void k_minmax(const float* __restrict__ maps, float* __restrict__ mm) {
    int m = blockIdx.x;
    const float* src = maps + (size_t)m * HW;
    float lo = 3.4e38f, hi = -3.4e38f;
    for (int i = threadIdx.x; i < HW; i += blockDim.x) {
        float v = src[i];
        lo = fminf(lo, v);
        hi = fmaxf(hi, v);
    }
    __shared__ float slo[256], shi[256];
    slo[threadIdx.x] = lo; shi[threadIdx.x] = hi;
    __syncthreads();
    for (int off = 128; off > 0; off >>= 1) {
        if (threadIdx.x < off) {
            slo[threadIdx.x] = fminf(slo[threadIdx.x], slo[threadIdx.x + off]);
            shi[threadIdx.x] = fmaxf(shi[threadIdx.x], shi[threadIdx.x + off]);
        }
        __syncthreads();
    }
    if (threadIdx.x == 0) { mm[m * 2] = slo[0]; mm[m * 2 + 1] = shi[0]; }
}

__global__ void k_init_bb(int* __restrict__ bb) {
    int i = blockIdx.x * blockDim.x + threadIdx.x;  // 1536 total
    bb[i] = INT_MAX;            // xmin
    bb[1536 + i] = INT_MIN;     // xmax
    bb[3072 + i] = INT_MAX;     // ymin
    bb[4608 + i] = INT_MIN;     // ymax
}

// ---- region sizes + bbox: LDS hist + LDS min/max, merged with global atomics ----
__global__ void k_region(const int* __restrict__ lab, float* __restrict__ rs_out, int* __restrict__ bb) {
    __shared__ unsigned cnt[NSEG];
    __shared__ int sxmin[NSEG], sxmax[NSEG], symin[NSEG], symax[NSEG];
    int big = blockIdx.y;  // b*3+g
    for (int i = threadIdx.x; i < NSEG; i += blockDim.x) {
        cnt[i] = 0; sxmin[i] = INT_MAX; sxmax[i] = INT_MIN; symin[i] = INT_MAX; symax[i] = INT_MIN;
    }
    __syncthreads();
    int stride = blockDim.x * gridDim.x;
    const int* lp = lab + (size_t)big * HW;
    for (int p = blockIdx.x * blockDim.x + threadIdx.x; p < HW; p += stride) {
        int l = lp[p] & 255;
        int y = p >> 9, x = p & 511;
        atomicAdd(&cnt[l], 1u);
        atomicMin(&sxmin[l], x); atomicMax(&sxmax[l], x);
        atomicMin(&symin[l], y); atomicMax(&symax[l], y);
    }
    __syncthreads();
    for (int i = threadIdx.x; i < NSEG; i += blockDim.x) {
        if (cnt[i]) atomicAdd(&rs_out[big * NSEG + i], (float)cnt[i]);
        if (sxmin[i] != INT_MAX) {
            atomicMin(&bb[big * NSEG + i], sxmin[i]);
            atomicMax(&bb[1536 + big * NSEG + i], sxmax[i]);
            atomicMin(&bb[3072 + big * NSEG + i], symin[i]);
            atomicMax(&bb[4608 + big * NSEG + i], symax[i]);
        }
    }
}

// ---- color histogram: per (b,g,c), 6400-bin LDS hist ----
__global__ void k_chist(const float* __restrict__ img, const int* __restrict__ lab, float* __restrict__ ch_out) {
    __shared__ unsigned cnt[NSEG * 25];
    int gy = blockIdx.y;       // (b*3+g)*3 + c
    int c = gy % 3;
    int bg = gy / 3;           // b*3+g
    int b = bg / 3;
    for (int i = threadIdx.x; i < NSEG * 25; i += blockDim.x) cnt[i] = 0;
    __syncthreads();
    const float* ip = img + ((size_t)b * 3 + c) * HW;
    const int* lp = lab + (size_t)bg * HW;
    int stride = blockDim.x * gridDim.x;
    for (int p = blockIdx.x * blockDim.x + threadIdx.x; p < HW; p += stride) {
        int l = lp[p] & 255;
        float v = ip[p];
        int bin = (int)((float)l * 25.0f + v * 24.0f);  // matches ref f32 op order
        bin = min(max(bin, 0), NSEG * 25 - 1);
        atomicAdd(&cnt[bin], 1u);
    }
    __syncthreads();
    for (int i = threadIdx.x; i < NSEG * 25; i += blockDim.x) {
        unsigned n = cnt[i];
        if (n) {
            int s = i / 25, cb = i - s * 25;
            atomicAdd(&ch_out[((size_t)(bg * NSEG + s) * 3 + c) * 25 + cb], (float)n);
        }
    }
}

// ---- texture histogram: per (b,c,t), 3 label maps x 2560-bin LDS hists ----
__global__ void k_thist(const float* __restrict__ maps, const int* __restrict__ lab,
                        const float* __restrict__ mm, float* __restrict__ th_out) {
    __shared__ unsigned cnt[3 * 2560];  // 30720 B
    int gy = blockIdx.y;    // bc*8 + t
    int t = gy & 7;
    int bc = gy >> 3;       // b*3+c
    int b = bc / 3;
    int c = bc - b * 3;
    int d = t & 1;
    int pos = (((t >> 1) & 1) == 0);
    int base = t >> 2;      // 0: g maps, 1: grc maps
    int m = base * 12 + bc * 2 + d;
    for (int i = threadIdx.x; i < 3 * 2560; i += blockDim.x) cnt[i] = 0;
    __syncthreads();
    float mn = mm[m * 2], mx = mm[m * 2 + 1];
    float hmin = pos ? fmaxf(mn, 0.f) : fminf(mn, 0.f);
    float hmax = pos ? fmaxf(mx, 0.f) : fminf(mx, 0.f);
    float den = hmax - hmin;
    const float* src = maps + (size_t)m * HW;
    const int* l0 = lab + (size_t)(b * 3 + 0) * HW;
    const int* l1 = lab + (size_t)(b * 3 + 1) * HW;
    const int* l2 = lab + (size_t)(b * 3 + 2) * HW;
    int stride = blockDim.x * gridDim.x;
    for (int p = blockIdx.x * blockDim.x + threadIdx.x; p < HW; p += stride) {
        float v = src[p];
        float vc = pos ? fmaxf(v, 0.f) : fminf(v, 0.f);
        float tn = (vc - hmin) / den;        // division, matching ref
        float t9 = tn * 9.0f;
        int la = l0[p] & 255, lb = l1[p] & 255, lc = l2[p] & 255;
        int b0 = (int)((float)la * 10.0f + t9);
        int b1 = (int)((float)lb * 10.0f + t9);
        int b2 = (int)((float)lc * 10.0f + t9);
        b0 = min(max(b0, 0), 2559); b1 = min(max(b1, 0), 2559); b2 = min(max(b2, 0), 2559);
        atomicAdd(&cnt[b0], 1u);
        atomicAdd(&cnt[2560 + b1], 1u);
        atomicAdd(&cnt[5120 + b2], 1u);
    }
    __syncthreads();
    for (int i = threadIdx.x; i < 3 * 2560; i += blockDim.x) {
        unsigned n = cnt[i];
        if (n) {
            int gi = i / 2560;
            int r = i - gi * 2560;
            int s = r / 10, tb = r - s * 10;
            // th layout: (B,I,G,S,C,8,10)
            size_t idx = ((size_t)((b * 3 + gi) * NSEG + s) * 3 + c) * 80 + t * 10 + tb;
            atomicAdd(&th_out[idx], (float)n);
        }
    }
}

// ---- normalize ch/th and write xywh ----
__global__ void k_final(float* __restrict__ out, const int* __restrict__ bb) {
    int seg = blockIdx.x;   // big*256 + s, 1536 total
    float rs = out[seg];
    float cd = 3.0f * rs;
    float td = 24.0f * rs;
    float* ch = out + CH_OFF + (size_t)seg * 75;
    float* th = out + TH_OFF + (size_t)seg * 240;
    for (int i = threadIdx.x; i < 75; i += blockDim.x) ch[i] = ch[i] / cd;
    for (int i = threadIdx.x; i < 240; i += blockDim.x) th[i] = th[i] / td;
    if (threadIdx.x == 0) {
        int xmin, xmax, ymin, ymax;
        if (rs > 0.f) {
            xmin = bb[seg]; xmax = bb[1536 + seg];
            ymin = bb[3072 + seg]; ymax = bb[4608 + seg];
        } else {
            xmin = IW; ymin = IW; xmax = 0; ymax = 0;
        }
        float* xy = out + XY_OFF + (size_t)seg * 4;
        xy[0] = (float)xmin; xy[1] = (float)ymin;
        xy[2] = (float)(xmax - xmin); xy[3] = (float)(ymax - ymin);
    }
}

extern "C" void kernel_launch(void* const* d_in, const int* in_sizes, int n_in,
                              void* d_out, int out_size, void* d_ws, size_t ws_size,
                              hipStream_t stream) {
    const float* img = (const float*)d_in[0];
    const int* lab = (const int*)d_in[1];
    float* out = (float*)d_out;

    float* ws = (float*)d_ws;
    float* rot = ws;                              // 6*725*725 = 3,153,750 f
    float* gmaps = rot + (size_t)6 * RHW;         // 12 maps * 262144
    float* grcmaps = gmaps + (size_t)12 * HW;     // 12 maps (contiguous after g)
    float* mm = grcmaps + (size_t)12 * HW;        // 48 floats
    int* bb = (int*)(mm + 48);                    // 4*1536 ints

    hipMemsetAsync(d_out, 0, (size_t)out_size * sizeof(float), stream);
    hipLaunchKernelGGL(k_init_bb, dim3(6), dim3(256), 0, stream, bb);
    hipLaunchKernelGGL(k_rot, dim3((RHW + 255) / 256, 6), dim3(256), 0, stream, img, rot);
    hipLaunchKernelGGL(k_scharr_img, dim3(HW / 256, 6), dim3(256), 0, stream, img, gmaps);
    hipLaunchKernelGGL(k_grc, dim3(HW / 256, 6), dim3(256), 0, stream, rot, grcmaps);
    hipLaunchKernelGGL(k_minmax, dim3(24), dim3(256), 0, stream, gmaps, mm);
    hipLaunchKernelGGL(k_region, dim3(32, 6), dim3(256), 0, stream, lab, out, bb);
    hipLaunchKernelGGL(k_chist, dim3(16, 18), dim3(256), 0, stream, img, lab, out + CH_OFF);
    hipLaunchKernelGGL(k_thist, dim3(8, 48), dim3(256), 0, stream, gmaps, lab, mm, out + TH_OFF);
    hipLaunchKernelGGL(k_final, dim3(1536), dim3(64), 0, stream, out, bb);
}